// Round 14
// baseline (166.673 us; speedup 1.0000x reference)
//
#include <hip/hip_runtime.h>

#define IN   128
#define HID  16
#define OUT  64
#define BK   64        // nodes per bucket (bucket = dst >> 6)
#define EPB  4096      // edges per partition block (B=196 blocks)
#define CAP  2048      // LDS staging capacity per bucket (mean ~1024)

__device__ __forceinline__ void f4add(float4& a, const float4 v) {
    a.x += v.x; a.y += v.y; a.z += v.z; a.w += v.w;
}

// ---- K1 (fused): blocks [0,nproj) = R12-proven proj; blocks [nproj,nproj+B) =
//      per-block bucket histogram (R5-proven heterogeneous fusion).
//      Block 0 also zeroes the scan-finisher ticket counter.
__global__ void __launch_bounds__(256)
k_proj_part1(const float* __restrict__ x,
             const float* __restrict__ Ws,
             const float* __restrict__ Wn,
             const int* __restrict__ dst,
             float* __restrict__ xs,
             float* __restrict__ xn,
             int* __restrict__ histT,
             int* __restrict__ counter,
             int n, int e, int nproj, int K, int B) {
    __shared__ __align__(16) float smem[4224 + 1024];  // proj: lwT+lx ; hist: lh
    int tid = threadIdx.x;   // 256
    if (blockIdx.x == 0 && tid == 0) *counter = 0;
    if ((int)blockIdx.x < nproj) {
        float (*lwT)[132] = (float (*)[132])smem;      // [32][132]
        float (*lx)[IN]   = (float (*)[IN])(smem + 4224);
        for (int i = tid; i < IN * 32; i += 256) {
            int k = i >> 5, j = i & 31;
            lwT[j][k] = (j < HID) ? Ws[k * HID + j] : Wn[k * HID + (j - 16)];
        }
        int node0 = blockIdx.x * 8;
        const float4* x4 = (const float4*)x;
        float4* lx4 = (float4*)lx;
        {
            int r = tid >> 5, c4 = tid & 31;
            int node = node0 + r;
            lx4[tid] = (node < n) ? x4[(size_t)node * 32 + c4]
                                  : make_float4(0.f, 0.f, 0.f, 0.f);
        }
        __syncthreads();
        int r = tid >> 5, j = tid & 31;
        int node = node0 + r;
        if (node >= n) return;
        const float4* lxr = (const float4*)lx[r];
        float acc = 0.f;
        #pragma unroll 4
        for (int k4 = 0; k4 < 32; ++k4) {
            float4 xv = lxr[k4];
            float4 wv = *(const float4*)&lwT[j][k4 * 4];
            acc += xv.x * wv.x + xv.y * wv.y + xv.z * wv.z + xv.w * wv.w;
        }
        if (j < HID) xs[(size_t)node * HID + j] = acc;
        else         xn[(size_t)node * HID + (j - 16)] = acc;
    } else {
        int* lh = (int*)smem;            // K <= 1024 counters
        int blk = blockIdx.x - nproj;
        for (int i = tid; i < K; i += 256) lh[i] = 0;
        __syncthreads();
        const int4* d4 = (const int4*)dst;
        #pragma unroll
        for (int it = 0; it < EPB / 1024; ++it) {   // 4 iters x 256 thr x 4 edges
            int i4 = blk * (EPB / 4) + it * 256 + tid;
            int elem = i4 * 4;
            if (elem + 3 < e) {
                int4 v = d4[i4];
                atomicAdd(&lh[v.x >> 6], 1);
                atomicAdd(&lh[v.y >> 6], 1);
                atomicAdd(&lh[v.z >> 6], 1);
                atomicAdd(&lh[v.w >> 6], 1);
            } else {
                for (int jj = elem; jj < e && jj < elem + 4; ++jj)
                    atomicAdd(&lh[dst[jj] >> 6], 1);
            }
        }
        __syncthreads();
        for (int b = tid; b < K; b += 256) histT[(size_t)blk * K + b] = lh[b];
    }
}

// ---- K2 (fused): per-bucket chunk scan (R11-proven rowscan body) + last-block
//      finisher performs the K-wide exclusive scan of btot -> boff.
__global__ void __launch_bounds__(256)
k_scan(int* __restrict__ histT, int* __restrict__ btot, int* __restrict__ boff,
       int* __restrict__ counter, int K, int B, int e) {
    __shared__ int sm[256];
    __shared__ int amlast;
    int b = blockIdx.x;
    int t = threadIdx.x;
    int v = (t < B) ? histT[(size_t)t * K + b] : 0;
    sm[t] = v;
    __syncthreads();
    for (int off = 1; off < 256; off <<= 1) {
        int u = (t >= off) ? sm[t - off] : 0;
        __syncthreads();
        sm[t] += u;
        __syncthreads();
    }
    if (t < B) histT[(size_t)t * K + b] = sm[t] - v;   // exclusive within row
    if (t == 255) btot[b] = sm[255];
    __threadfence();                     // publish btot[b] before taking ticket
    __syncthreads();
    if (t == 0) amlast = (atomicAdd(counter, 1) == K - 1) ? 1 : 0;
    __syncthreads();
    if (!amlast) return;
    // finisher: exclusive scan of btot[0..K-1] -> boff (256 thr x C chunks)
    int C = (K + 255) >> 8;
    int i0 = t * C, i1 = min(i0 + C, K);
    int s = 0;
    for (int i = i0; i < i1; ++i) s += btot[i];
    sm[t] = s;
    __syncthreads();
    for (int off = 1; off < 256; off <<= 1) {
        int u = (t >= off) ? sm[t - off] : 0;
        __syncthreads();
        sm[t] += u;
        __syncthreads();
    }
    int run = sm[t] - s;
    for (int i = i0; i < i1; ++i) {
        int vv = btot[i];
        boff[i] = run;
        run += vv;
    }
    if (t == 0) boff[K] = e;
}

// ---- K3: scatter; base = boff[b] + histT[blk*K+b]  (R13-proven)
__global__ void __launch_bounds__(512)
k_part2(const int* __restrict__ src, const int* __restrict__ dst,
        const int* __restrict__ histT, const int* __restrict__ boff,
        unsigned* __restrict__ bedge, int e, int K, int B) {
    __shared__ int lbase[1024];
    int tid = threadIdx.x, blk = blockIdx.x;
    for (int b = tid; b < K; b += 512)
        lbase[b] = boff[b] + histT[(size_t)blk * K + b];
    __syncthreads();
    const int4* s4 = (const int4*)src;
    const int4* d4 = (const int4*)dst;
    #pragma unroll
    for (int it = 0; it < EPB / 2048; ++it) {
        int i4 = blk * (EPB / 4) + it * 512 + tid;
        int elem = i4 * 4;
        if (elem + 3 < e) {
            int4 sv = s4[i4];
            int4 dv = d4[i4];
            int p0 = atomicAdd(&lbase[dv.x >> 6], 1);
            int p1 = atomicAdd(&lbase[dv.y >> 6], 1);
            int p2 = atomicAdd(&lbase[dv.z >> 6], 1);
            int p3 = atomicAdd(&lbase[dv.w >> 6], 1);
            bedge[p0] = ((unsigned)sv.x << 6) | (unsigned)(dv.x & 63);
            bedge[p1] = ((unsigned)sv.y << 6) | (unsigned)(dv.y & 63);
            bedge[p2] = ((unsigned)sv.z << 6) | (unsigned)(dv.z & 63);
            bedge[p3] = ((unsigned)sv.w << 6) | (unsigned)(dv.w & 63);
        } else {
            for (int j = elem; j < e && j < elem + 4; ++j) {
                int pos = atomicAdd(&lbase[dst[j] >> 6], 1);
                bedge[pos] = ((unsigned)src[j] << 6) | (unsigned)(dst[j] & 63);
            }
        }
    }
}

// ---- K4: per-bucket fine segmentation + float4 register pull + relu finish.
__global__ void __launch_bounds__(512)
k_agg1(const unsigned* __restrict__ bedge, const int* __restrict__ boff,
       const float* __restrict__ xs, const float* __restrict__ xn,
       const float* __restrict__ b1, float* __restrict__ h,
       int* __restrict__ fsrc, int* __restrict__ rowptr, int n, int K) {
    __shared__ int ltmp[CAP];
    __shared__ int lsrc[CAP];
    __shared__ int lcnt[BK];
    __shared__ int lofs[BK + 1];
    __shared__ int lcur[BK];
    int tid = threadIdx.x, b = blockIdx.x;
    int s0 = boff[b], s1 = boff[b + 1], cnt = s1 - s0;
    bool fits = (cnt <= CAP);
    if (tid < BK) lcnt[tid] = 0;
    __syncthreads();
    if (fits) {
        for (int i = tid; i < cnt; i += 512) {
            int p = (int)bedge[s0 + i];
            ltmp[i] = p;
            atomicAdd(&lcnt[p & 63], 1);
        }
    } else {
        for (int i = tid; i < cnt; i += 512)
            atomicAdd(&lcnt[(int)bedge[s0 + i] & 63], 1);
    }
    __syncthreads();
    if (tid < BK) {
        int v = lcnt[tid];
        #pragma unroll
        for (int off = 1; off < 64; off <<= 1) {
            int t = __shfl_up(v, off);
            if (tid >= off) v += t;
        }
        lofs[tid + 1] = v;
        if (tid == 0) lofs[0] = 0;
        lcur[tid] = lofs[tid];
    }
    __syncthreads();
    if (fits) {
        for (int i = tid; i < cnt; i += 512) {
            int p = ltmp[i];
            int r = atomicAdd(&lcur[p & 63], 1);
            lsrc[r] = p >> 6;
        }
    } else {
        for (int i = tid; i < cnt; i += 512) {
            int p = (int)bedge[s0 + i];
            int r = atomicAdd(&lcur[p & 63], 1);
            fsrc[s0 + r] = p >> 6;
        }
        __threadfence_block();
    }
    __syncthreads();
    if (fits)
        for (int i = tid; i < cnt; i += 512) fsrc[s0 + i] = lsrc[i];
    int node0 = b * BK;
    if (tid < BK) rowptr[node0 + tid] = s0 + lofs[tid];
    if (b == K - 1 && tid == 0) rowptr[node0 + BK] = s1;
    // float4 pull: tid = nl*8 + half*4 + d4
    int d4 = tid & 3;
    int half = (tid >> 2) & 1;
    int nl = tid >> 3;
    int node = node0 + nl;
    int t0 = lofs[nl], t1 = lofs[nl + 1];
    const float4* xn4 = (const float4*)xn;
    float4 a0 = make_float4(0.f, 0.f, 0.f, 0.f);
    float4 a1 = make_float4(0.f, 0.f, 0.f, 0.f);
    int k = t0 + half;
    if (fits) {
        for (; k + 2 < t1; k += 4) {
            f4add(a0, xn4[(size_t)lsrc[k] * 4 + d4]);
            f4add(a1, xn4[(size_t)lsrc[k + 2] * 4 + d4]);
        }
        if (k < t1) f4add(a0, xn4[(size_t)lsrc[k] * 4 + d4]);
    } else {
        for (; k < t1; k += 2) f4add(a0, xn4[(size_t)fsrc[s0 + k] * 4 + d4]);
    }
    f4add(a0, a1);
    a0.x += __shfl_xor(a0.x, 4);
    a0.y += __shfl_xor(a0.y, 4);
    a0.z += __shfl_xor(a0.z, 4);
    a0.w += __shfl_xor(a0.w, 4);
    if (half == 0 && node < n) {
        float inv = 1.0f / fmaxf((float)(t1 - t0), 1.0f);
        float4 xv = ((const float4*)xs)[(size_t)node * 4 + d4];
        float4 bv = ((const float4*)b1)[d4];
        float4 hv;
        hv.x = fmaxf(xv.x + a0.x * inv + bv.x, 0.f);
        hv.y = fmaxf(xv.y + a0.y * inv + bv.y, 0.f);
        hv.z = fmaxf(xv.z + a0.z * inv + bv.z, 0.f);
        hv.w = fmaxf(xv.w + a0.w * inv + bv.w, 0.f);
        ((float4*)h)[(size_t)node * 4 + d4] = hv;
    }
}

// ---- K5: per-bucket float4 pull of h + fused output GEMM.
__global__ void __launch_bounds__(512)
k_agg2_out(const int* __restrict__ fsrc, const int* __restrict__ rowptr,
           const float* __restrict__ h,
           const float* __restrict__ Ws2, const float* __restrict__ Wn2,
           const float* __restrict__ b2, float* __restrict__ out, int n) {
    __shared__ int   lidx[CAP];
    __shared__ int   lofs[BK + 1];
    __shared__ float lh[BK][HID];
    __shared__ float lagg[BK][HID];
    __shared__ float lws[HID][OUT];
    __shared__ float lwn[HID][OUT];
    __shared__ float lb2v[OUT];
    int tid = threadIdx.x, b = blockIdx.x;
    int node0 = b * BK;
    int s0r = rowptr[node0];
    int s1r = rowptr[node0 + BK];
    int cnt = s1r - s0r;
    bool fits = (cnt <= CAP);
    if (tid <= BK) lofs[tid] = rowptr[node0 + tid] - s0r;
    if (fits)
        for (int i = tid; i < cnt; i += 512) lidx[i] = fsrc[s0r + i];
    for (int i = tid; i < BK * HID; i += 512) {
        int node = node0 + (i >> 4);
        lh[i >> 4][i & 15] = (node < n) ? h[(size_t)node * HID + (i & 15)] : 0.f;
    }
    for (int i = tid; i < HID * OUT; i += 512) {
        ((float*)lws)[i] = Ws2[i];
        ((float*)lwn)[i] = Wn2[i];
    }
    if (tid < OUT) lb2v[tid] = b2[tid];
    __syncthreads();
    int d4 = tid & 3;
    int half = (tid >> 2) & 1;
    int nl = tid >> 3;
    int t0 = lofs[nl], t1 = lofs[nl + 1];
    const float4* h4 = (const float4*)h;
    float4 a0 = make_float4(0.f, 0.f, 0.f, 0.f);
    float4 a1 = make_float4(0.f, 0.f, 0.f, 0.f);
    int k = t0 + half;
    if (fits) {
        for (; k + 2 < t1; k += 4) {
            f4add(a0, h4[(size_t)lidx[k] * 4 + d4]);
            f4add(a1, h4[(size_t)lidx[k + 2] * 4 + d4]);
        }
        if (k < t1) f4add(a0, h4[(size_t)lidx[k] * 4 + d4]);
    } else {
        for (; k < t1; k += 2) f4add(a0, h4[(size_t)fsrc[s0r + k] * 4 + d4]);
    }
    f4add(a0, a1);
    a0.x += __shfl_xor(a0.x, 4);
    a0.y += __shfl_xor(a0.y, 4);
    a0.z += __shfl_xor(a0.z, 4);
    a0.w += __shfl_xor(a0.w, 4);
    if (half == 0) {
        float inv = 1.0f / fmaxf((float)(t1 - t0), 1.0f);
        float4 r;
        r.x = a0.x * inv; r.y = a0.y * inv; r.z = a0.z * inv; r.w = a0.w * inv;
        *(float4*)&lagg[nl][d4 * 4] = r;
    }
    __syncthreads();
    for (int i = tid; i < BK * OUT; i += 512) {
        int nl2 = i >> 6, o = i & 63;
        int node = node0 + nl2;
        if (node >= n) continue;
        float acm = lb2v[o];
        #pragma unroll
        for (int j = 0; j < HID; ++j)
            acm += lh[nl2][j] * lws[j][o] + lagg[nl2][j] * lwn[j][o];
        out[(size_t)node * OUT + o] = acm;
    }
}

extern "C" void kernel_launch(void* const* d_in, const int* in_sizes, int n_in,
                              void* d_out, int out_size, void* d_ws, size_t ws_size,
                              hipStream_t stream) {
    const float* x   = (const float*)d_in[0];
    const int*   src = (const int*)d_in[1];
    const int*   dst = (const int*)d_in[2];
    const float* Ws1 = (const float*)d_in[3];
    const float* Wn1 = (const float*)d_in[4];
    const float* b1  = (const float*)d_in[5];
    const float* Ws2 = (const float*)d_in[6];
    const float* Wn2 = (const float*)d_in[7];
    const float* b2  = (const float*)d_in[8];
    float* out = (float*)d_out;

    int n = in_sizes[0] / IN;          // 50000
    int e = in_sizes[1];               // 800000
    int K = (n + BK - 1) / BK;         // 782 buckets
    int B = (e + EPB - 1) / EPB;       // 196 partition blocks
    int T = K * B;
    int nproj = (n + 7) / 8;           // 6250 proj blocks

    // ws: counter[1] | histT[T] | btot[K] | boff[K+1] | rowptr[K*BK+1] | bedge[e] | fsrc[e] | xs | xn | h
    int* counter = (int*)d_ws;
    int* histT  = counter + 1;
    int* btot   = histT + T;
    int* boff   = btot + K;
    int* rowptr = boff + (K + 1);
    unsigned* bedge = (unsigned*)(rowptr + ((size_t)K * BK + 1));
    int* fsrc = (int*)(bedge + e);
    float* xs = (float*)(fsrc + e);
    float* xn = xs + (size_t)n * HID;
    float* h  = xn + (size_t)n * HID;

    k_proj_part1<<<nproj + B, 256, 0, stream>>>(x, Ws1, Wn1, dst, xs, xn,
                                                histT, counter, n, e, nproj, K, B);
    k_scan<<<K, 256, 0, stream>>>(histT, btot, boff, counter, K, B, e);
    k_part2<<<B, 512, 0, stream>>>(src, dst, histT, boff, bedge, e, K, B);

    k_agg1<<<K, 512, 0, stream>>>(bedge, boff, xs, xn, b1, h, fsrc, rowptr, n, K);
    k_agg2_out<<<K, 512, 0, stream>>>(fsrc, rowptr, h, Ws2, Wn2, b2, out, n);
}

// Round 15
// 79.093 us; speedup vs baseline: 2.1073x; 2.1073x over previous
//
#include <hip/hip_runtime.h>

#define IN   128
#define HID  16
#define OUT  64
#define BK   64        // nodes per bucket (bucket = dst >> 6)
#define EPB  4096      // edges per partition block (B=196 blocks)
#define CAP  2048      // LDS staging capacity per bucket (mean ~1024)

__device__ __forceinline__ void f4add(float4& a, const float4 v) {
    a.x += v.x; a.y += v.y; a.z += v.z; a.w += v.w;
}

// ---- K1 (fused): blocks [0,nproj) = R12-proven proj; blocks [nproj,nproj+B) =
//      per-block bucket histogram. (R14-proven fusion, ~9 us saved.)
__global__ void __launch_bounds__(256)
k_proj_part1(const float* __restrict__ x,
             const float* __restrict__ Ws,
             const float* __restrict__ Wn,
             const int* __restrict__ dst,
             float* __restrict__ xs,
             float* __restrict__ xn,
             int* __restrict__ histT,
             int n, int e, int nproj, int K, int B) {
    __shared__ __align__(16) float smem[4224 + 1024];  // proj: lwT+lx ; hist: lh
    int tid = threadIdx.x;   // 256
    if ((int)blockIdx.x < nproj) {
        float (*lwT)[132] = (float (*)[132])smem;      // [32][132]
        float (*lx)[IN]   = (float (*)[IN])(smem + 4224);
        for (int i = tid; i < IN * 32; i += 256) {
            int k = i >> 5, j = i & 31;
            lwT[j][k] = (j < HID) ? Ws[k * HID + j] : Wn[k * HID + (j - 16)];
        }
        int node0 = blockIdx.x * 8;
        const float4* x4 = (const float4*)x;
        float4* lx4 = (float4*)lx;
        {
            int r = tid >> 5, c4 = tid & 31;
            int node = node0 + r;
            lx4[tid] = (node < n) ? x4[(size_t)node * 32 + c4]
                                  : make_float4(0.f, 0.f, 0.f, 0.f);
        }
        __syncthreads();
        int r = tid >> 5, j = tid & 31;
        int node = node0 + r;
        if (node >= n) return;
        const float4* lxr = (const float4*)lx[r];
        float acc = 0.f;
        #pragma unroll 4
        for (int k4 = 0; k4 < 32; ++k4) {
            float4 xv = lxr[k4];
            float4 wv = *(const float4*)&lwT[j][k4 * 4];
            acc += xv.x * wv.x + xv.y * wv.y + xv.z * wv.z + xv.w * wv.w;
        }
        if (j < HID) xs[(size_t)node * HID + j] = acc;
        else         xn[(size_t)node * HID + (j - 16)] = acc;
    } else {
        int* lh = (int*)smem;            // K <= 1024 counters
        int blk = blockIdx.x - nproj;
        for (int i = tid; i < K; i += 256) lh[i] = 0;
        __syncthreads();
        const int4* d4 = (const int4*)dst;
        #pragma unroll
        for (int it = 0; it < EPB / 1024; ++it) {   // 4 iters x 256 thr x 4 edges
            int i4 = blk * (EPB / 4) + it * 256 + tid;
            int elem = i4 * 4;
            if (elem + 3 < e) {
                int4 v = d4[i4];
                atomicAdd(&lh[v.x >> 6], 1);
                atomicAdd(&lh[v.y >> 6], 1);
                atomicAdd(&lh[v.z >> 6], 1);
                atomicAdd(&lh[v.w >> 6], 1);
            } else {
                for (int jj = elem; jj < e && jj < elem + 4; ++jj)
                    atomicAdd(&lh[dst[jj] >> 6], 1);
            }
        }
        __syncthreads();
        for (int b = tid; b < K; b += 256) histT[(size_t)blk * K + b] = lh[b];
    }
}

// ---- K2: one BLOCK per bucket: LDS-scan the B (<=256) chunk counts in place.
//      (R13-proven; no fences, no tickets.)
__global__ void __launch_bounds__(256)
k_rowscan(int* __restrict__ histT, int* __restrict__ btot, int K, int B) {
    __shared__ int sm[256];
    int b = blockIdx.x;
    int t = threadIdx.x;
    int v = (t < B) ? histT[(size_t)t * K + b] : 0;
    sm[t] = v;
    __syncthreads();
    for (int off = 1; off < 256; off <<= 1) {
        int u = (t >= off) ? sm[t - off] : 0;
        __syncthreads();
        sm[t] += u;
        __syncthreads();
    }
    if (t < B) histT[(size_t)t * K + b] = sm[t] - v;
    if (t == 255) btot[b] = sm[255];
}

// ---- K3: exclusive scan of K bucket totals (K <= 1024), LDS only
__global__ void __launch_bounds__(1024)
k_scanB(const int* __restrict__ btot, int* __restrict__ boff, int K, int e) {
    __shared__ int sm[1024];
    int tid = threadIdx.x;
    int v = (tid < K) ? btot[tid] : 0;
    sm[tid] = v;
    __syncthreads();
    for (int off = 1; off < 1024; off <<= 1) {
        int t = (tid >= off) ? sm[tid - off] : 0;
        __syncthreads();
        sm[tid] += t;
        __syncthreads();
    }
    if (tid < K) boff[tid] = sm[tid] - v;
    if (tid == 0) boff[K] = e;
}

// ---- K4: scatter; base = boff[b] + histT[blk*K+b]  (R13-proven)
__global__ void __launch_bounds__(512)
k_part2(const int* __restrict__ src, const int* __restrict__ dst,
        const int* __restrict__ histT, const int* __restrict__ boff,
        unsigned* __restrict__ bedge, int e, int K, int B) {
    __shared__ int lbase[1024];
    int tid = threadIdx.x, blk = blockIdx.x;
    for (int b = tid; b < K; b += 512)
        lbase[b] = boff[b] + histT[(size_t)blk * K + b];
    __syncthreads();
    const int4* s4 = (const int4*)src;
    const int4* d4 = (const int4*)dst;
    #pragma unroll
    for (int it = 0; it < EPB / 2048; ++it) {
        int i4 = blk * (EPB / 4) + it * 512 + tid;
        int elem = i4 * 4;
        if (elem + 3 < e) {
            int4 sv = s4[i4];
            int4 dv = d4[i4];
            int p0 = atomicAdd(&lbase[dv.x >> 6], 1);
            int p1 = atomicAdd(&lbase[dv.y >> 6], 1);
            int p2 = atomicAdd(&lbase[dv.z >> 6], 1);
            int p3 = atomicAdd(&lbase[dv.w >> 6], 1);
            bedge[p0] = ((unsigned)sv.x << 6) | (unsigned)(dv.x & 63);
            bedge[p1] = ((unsigned)sv.y << 6) | (unsigned)(dv.y & 63);
            bedge[p2] = ((unsigned)sv.z << 6) | (unsigned)(dv.z & 63);
            bedge[p3] = ((unsigned)sv.w << 6) | (unsigned)(dv.w & 63);
        } else {
            for (int j = elem; j < e && j < elem + 4; ++j) {
                int pos = atomicAdd(&lbase[dst[j] >> 6], 1);
                bedge[pos] = ((unsigned)src[j] << 6) | (unsigned)(dst[j] & 63);
            }
        }
    }
}

// ---- K5: per-bucket fine segmentation + float4 register pull + relu finish.
__global__ void __launch_bounds__(512)
k_agg1(const unsigned* __restrict__ bedge, const int* __restrict__ boff,
       const float* __restrict__ xs, const float* __restrict__ xn,
       const float* __restrict__ b1, float* __restrict__ h,
       int* __restrict__ fsrc, int* __restrict__ rowptr, int n, int K) {
    __shared__ int ltmp[CAP];
    __shared__ int lsrc[CAP];
    __shared__ int lcnt[BK];
    __shared__ int lofs[BK + 1];
    __shared__ int lcur[BK];
    int tid = threadIdx.x, b = blockIdx.x;
    int s0 = boff[b], s1 = boff[b + 1], cnt = s1 - s0;
    bool fits = (cnt <= CAP);
    if (tid < BK) lcnt[tid] = 0;
    __syncthreads();
    if (fits) {
        for (int i = tid; i < cnt; i += 512) {
            int p = (int)bedge[s0 + i];
            ltmp[i] = p;
            atomicAdd(&lcnt[p & 63], 1);
        }
    } else {
        for (int i = tid; i < cnt; i += 512)
            atomicAdd(&lcnt[(int)bedge[s0 + i] & 63], 1);
    }
    __syncthreads();
    if (tid < BK) {
        int v = lcnt[tid];
        #pragma unroll
        for (int off = 1; off < 64; off <<= 1) {
            int t = __shfl_up(v, off);
            if (tid >= off) v += t;
        }
        lofs[tid + 1] = v;
        if (tid == 0) lofs[0] = 0;
        lcur[tid] = lofs[tid];
    }
    __syncthreads();
    if (fits) {
        for (int i = tid; i < cnt; i += 512) {
            int p = ltmp[i];
            int r = atomicAdd(&lcur[p & 63], 1);
            lsrc[r] = p >> 6;
        }
    } else {
        for (int i = tid; i < cnt; i += 512) {
            int p = (int)bedge[s0 + i];
            int r = atomicAdd(&lcur[p & 63], 1);
            fsrc[s0 + r] = p >> 6;
        }
        __threadfence_block();
    }
    __syncthreads();
    if (fits)
        for (int i = tid; i < cnt; i += 512) fsrc[s0 + i] = lsrc[i];
    int node0 = b * BK;
    if (tid < BK) rowptr[node0 + tid] = s0 + lofs[tid];
    if (b == K - 1 && tid == 0) rowptr[node0 + BK] = s1;
    // float4 pull: tid = nl*8 + half*4 + d4
    int d4 = tid & 3;
    int half = (tid >> 2) & 1;
    int nl = tid >> 3;
    int node = node0 + nl;
    int t0 = lofs[nl], t1 = lofs[nl + 1];
    const float4* xn4 = (const float4*)xn;
    float4 a0 = make_float4(0.f, 0.f, 0.f, 0.f);
    float4 a1 = make_float4(0.f, 0.f, 0.f, 0.f);
    int k = t0 + half;
    if (fits) {
        for (; k + 2 < t1; k += 4) {
            f4add(a0, xn4[(size_t)lsrc[k] * 4 + d4]);
            f4add(a1, xn4[(size_t)lsrc[k + 2] * 4 + d4]);
        }
        if (k < t1) f4add(a0, xn4[(size_t)lsrc[k] * 4 + d4]);
    } else {
        for (; k < t1; k += 2) f4add(a0, xn4[(size_t)fsrc[s0 + k] * 4 + d4]);
    }
    f4add(a0, a1);
    a0.x += __shfl_xor(a0.x, 4);
    a0.y += __shfl_xor(a0.y, 4);
    a0.z += __shfl_xor(a0.z, 4);
    a0.w += __shfl_xor(a0.w, 4);
    if (half == 0 && node < n) {
        float inv = 1.0f / fmaxf((float)(t1 - t0), 1.0f);
        float4 xv = ((const float4*)xs)[(size_t)node * 4 + d4];
        float4 bv = ((const float4*)b1)[d4];
        float4 hv;
        hv.x = fmaxf(xv.x + a0.x * inv + bv.x, 0.f);
        hv.y = fmaxf(xv.y + a0.y * inv + bv.y, 0.f);
        hv.z = fmaxf(xv.z + a0.z * inv + bv.z, 0.f);
        hv.w = fmaxf(xv.w + a0.w * inv + bv.w, 0.f);
        ((float4*)h)[(size_t)node * 4 + d4] = hv;
    }
}

// ---- K6: per-bucket float4 pull of h + fused output GEMM.
__global__ void __launch_bounds__(512)
k_agg2_out(const int* __restrict__ fsrc, const int* __restrict__ rowptr,
           const float* __restrict__ h,
           const float* __restrict__ Ws2, const float* __restrict__ Wn2,
           const float* __restrict__ b2, float* __restrict__ out, int n) {
    __shared__ int   lidx[CAP];
    __shared__ int   lofs[BK + 1];
    __shared__ float lh[BK][HID];
    __shared__ float lagg[BK][HID];
    __shared__ float lws[HID][OUT];
    __shared__ float lwn[HID][OUT];
    __shared__ float lb2v[OUT];
    int tid = threadIdx.x, b = blockIdx.x;
    int node0 = b * BK;
    int s0r = rowptr[node0];
    int s1r = rowptr[node0 + BK];
    int cnt = s1r - s0r;
    bool fits = (cnt <= CAP);
    if (tid <= BK) lofs[tid] = rowptr[node0 + tid] - s0r;
    if (fits)
        for (int i = tid; i < cnt; i += 512) lidx[i] = fsrc[s0r + i];
    for (int i = tid; i < BK * HID; i += 512) {
        int node = node0 + (i >> 4);
        lh[i >> 4][i & 15] = (node < n) ? h[(size_t)node * HID + (i & 15)] : 0.f;
    }
    for (int i = tid; i < HID * OUT; i += 512) {
        ((float*)lws)[i] = Ws2[i];
        ((float*)lwn)[i] = Wn2[i];
    }
    if (tid < OUT) lb2v[tid] = b2[tid];
    __syncthreads();
    int d4 = tid & 3;
    int half = (tid >> 2) & 1;
    int nl = tid >> 3;
    int t0 = lofs[nl], t1 = lofs[nl + 1];
    const float4* h4 = (const float4*)h;
    float4 a0 = make_float4(0.f, 0.f, 0.f, 0.f);
    float4 a1 = make_float4(0.f, 0.f, 0.f, 0.f);
    int k = t0 + half;
    if (fits) {
        for (; k + 2 < t1; k += 4) {
            f4add(a0, h4[(size_t)lidx[k] * 4 + d4]);
            f4add(a1, h4[(size_t)lidx[k + 2] * 4 + d4]);
        }
        if (k < t1) f4add(a0, h4[(size_t)lidx[k] * 4 + d4]);
    } else {
        for (; k < t1; k += 2) f4add(a0, h4[(size_t)fsrc[s0r + k] * 4 + d4]);
    }
    f4add(a0, a1);
    a0.x += __shfl_xor(a0.x, 4);
    a0.y += __shfl_xor(a0.y, 4);
    a0.z += __shfl_xor(a0.z, 4);
    a0.w += __shfl_xor(a0.w, 4);
    if (half == 0) {
        float inv = 1.0f / fmaxf((float)(t1 - t0), 1.0f);
        float4 r;
        r.x = a0.x * inv; r.y = a0.y * inv; r.z = a0.z * inv; r.w = a0.w * inv;
        *(float4*)&lagg[nl][d4 * 4] = r;
    }
    __syncthreads();
    for (int i = tid; i < BK * OUT; i += 512) {
        int nl2 = i >> 6, o = i & 63;
        int node = node0 + nl2;
        if (node >= n) continue;
        float acm = lb2v[o];
        #pragma unroll
        for (int j = 0; j < HID; ++j)
            acm += lh[nl2][j] * lws[j][o] + lagg[nl2][j] * lwn[j][o];
        out[(size_t)node * OUT + o] = acm;
    }
}

extern "C" void kernel_launch(void* const* d_in, const int* in_sizes, int n_in,
                              void* d_out, int out_size, void* d_ws, size_t ws_size,
                              hipStream_t stream) {
    const float* x   = (const float*)d_in[0];
    const int*   src = (const int*)d_in[1];
    const int*   dst = (const int*)d_in[2];
    const float* Ws1 = (const float*)d_in[3];
    const float* Wn1 = (const float*)d_in[4];
    const float* b1  = (const float*)d_in[5];
    const float* Ws2 = (const float*)d_in[6];
    const float* Wn2 = (const float*)d_in[7];
    const float* b2  = (const float*)d_in[8];
    float* out = (float*)d_out;

    int n = in_sizes[0] / IN;          // 50000
    int e = in_sizes[1];               // 800000
    int K = (n + BK - 1) / BK;         // 782 buckets
    int B = (e + EPB - 1) / EPB;       // 196 partition blocks
    int T = K * B;
    int nproj = (n + 7) / 8;           // 6250 proj blocks

    // ws: histT[T] | btot[K] | boff[K+1] | rowptr[K*BK+1] | bedge[e] | fsrc[e] | xs | xn | h
    int* histT  = (int*)d_ws;
    int* btot   = histT + T;
    int* boff   = btot + K;
    int* rowptr = boff + (K + 1);
    unsigned* bedge = (unsigned*)(rowptr + ((size_t)K * BK + 1));
    int* fsrc = (int*)(bedge + e);
    float* xs = (float*)(fsrc + e);
    float* xn = xs + (size_t)n * HID;
    float* h  = xn + (size_t)n * HID;

    k_proj_part1<<<nproj + B, 256, 0, stream>>>(x, Ws1, Wn1, dst, xs, xn,
                                                histT, n, e, nproj, K, B);
    k_rowscan<<<K, 256, 0, stream>>>(histT, btot, K, B);
    k_scanB<<<1, 1024, 0, stream>>>(btot, boff, K, e);
    k_part2<<<B, 512, 0, stream>>>(src, dst, histT, boff, bedge, e, K, B);

    k_agg1<<<K, 512, 0, stream>>>(bedge, boff, xs, xn, b1, h, fsrc, rowptr, n, K);
    k_agg2_out<<<K, 512, 0, stream>>>(fsrc, rowptr, h, Ws2, Wn2, b2, out, n);
}

// Round 16
// 74.360 us; speedup vs baseline: 2.2414x; 1.0637x over previous
//
#include <hip/hip_runtime.h>

#define IN   128
#define HID  16
#define OUT  64
#define BK   64        // nodes per bucket (bucket = dst >> 6)
#define EPB  4096      // edges per partition block (B=196 blocks)
#define CAP  2048      // staging capacity per bucket (mean ~1024, 30-sigma safe)

__device__ __forceinline__ void f4add(float4& a, const float4 v) {
    a.x += v.x; a.y += v.y; a.z += v.z; a.w += v.w;
}

// ---- K1 (fused): blocks [0,nproj) = R12-proven proj.
//      blocks [nproj,nproj+B): fully BLOCK-LOCAL partition: hist -> local scan
//      -> scatter to private bedge region; writes loffT[b][blk] (no cross-block
//      coordination, no fences -- R14 lesson).
__global__ void __launch_bounds__(256)
k_proj_part(const float* __restrict__ x,
            const float* __restrict__ Ws,
            const float* __restrict__ Wn,
            const int* __restrict__ src,
            const int* __restrict__ dst,
            float* __restrict__ xs,
            float* __restrict__ xn,
            int* __restrict__ loffT,
            unsigned* __restrict__ bedge,
            int n, int e, int nproj, int K, int B) {
    __shared__ __align__(16) float smem[4224 + 1024];  // proj overlay / part overlay
    int tid = threadIdx.x;   // 256
    if ((int)blockIdx.x < nproj) {
        float (*lwT)[132] = (float (*)[132])smem;      // [32][132]
        float (*lx)[IN]   = (float (*)[IN])(smem + 4224);
        for (int i = tid; i < IN * 32; i += 256) {
            int k = i >> 5, j = i & 31;
            lwT[j][k] = (j < HID) ? Ws[k * HID + j] : Wn[k * HID + (j - 16)];
        }
        int node0 = blockIdx.x * 8;
        const float4* x4 = (const float4*)x;
        float4* lx4 = (float4*)lx;
        {
            int r = tid >> 5, c4 = tid & 31;
            int node = node0 + r;
            lx4[tid] = (node < n) ? x4[(size_t)node * 32 + c4]
                                  : make_float4(0.f, 0.f, 0.f, 0.f);
        }
        __syncthreads();
        int r = tid >> 5, j = tid & 31;
        int node = node0 + r;
        if (node >= n) return;
        const float4* lxr = (const float4*)lx[r];
        float acc = 0.f;
        #pragma unroll 4
        for (int k4 = 0; k4 < 32; ++k4) {
            float4 xv = lxr[k4];
            float4 wv = *(const float4*)&lwT[j][k4 * 4];
            acc += xv.x * wv.x + xv.y * wv.y + xv.z * wv.z + xv.w * wv.w;
        }
        if (j < HID) xs[(size_t)node * HID + j] = acc;
        else         xn[(size_t)node * HID + (j - 16)] = acc;
    } else {
        int* ism = (int*)smem;
        int* lh  = ism;            // [1024] counts, later cursors
        int* lsc = ism + 1024;     // [K+1] exclusive scan
        int* sm  = ism + 2050;     // [256] scan temp
        int blk = blockIdx.x - nproj;
        for (int i = tid; i < K; i += 256) lh[i] = 0;
        __syncthreads();
        const int4* d4 = (const int4*)dst;
        #pragma unroll
        for (int it = 0; it < EPB / 1024; ++it) {
            int i4 = blk * (EPB / 4) + it * 256 + tid;
            int elem = i4 * 4;
            if (elem + 3 < e) {
                int4 v = d4[i4];
                atomicAdd(&lh[v.x >> 6], 1);
                atomicAdd(&lh[v.y >> 6], 1);
                atomicAdd(&lh[v.z >> 6], 1);
                atomicAdd(&lh[v.w >> 6], 1);
            } else {
                for (int jj = elem; jj < e && jj < elem + 4; ++jj)
                    atomicAdd(&lh[dst[jj] >> 6], 1);
            }
        }
        __syncthreads();
        // block-local exclusive scan of lh[0..K-1] -> lsc (R14-finisher body)
        int C = (K + 255) >> 8;
        int i0 = tid * C, i1 = min(i0 + C, K);
        int s = 0;
        for (int i = i0; i < i1; ++i) s += lh[i];
        sm[tid] = s;
        __syncthreads();
        for (int off = 1; off < 256; off <<= 1) {
            int u = (tid >= off) ? sm[tid - off] : 0;
            __syncthreads();
            sm[tid] += u;
            __syncthreads();
        }
        int run = sm[tid] - s;
        for (int i = i0; i < i1; ++i) {
            int vv = lh[i];
            lsc[i] = run;
            run += vv;
        }
        if (tid == 255) lsc[K] = sm[255];
        __syncthreads();
        for (int bb = tid; bb <= K; bb += 256)
            loffT[(size_t)bb * B + blk] = lsc[bb];
        for (int bb = tid; bb < K; bb += 256) lh[bb] = lsc[bb];  // cursors
        __syncthreads();
        unsigned base = (unsigned)blk * EPB;
        const int4* s4 = (const int4*)src;
        #pragma unroll
        for (int it = 0; it < EPB / 1024; ++it) {
            int i4 = blk * (EPB / 4) + it * 256 + tid;
            int elem = i4 * 4;
            if (elem + 3 < e) {
                int4 sv = s4[i4];
                int4 dv = d4[i4];
                int p0 = atomicAdd(&lh[dv.x >> 6], 1);
                int p1 = atomicAdd(&lh[dv.y >> 6], 1);
                int p2 = atomicAdd(&lh[dv.z >> 6], 1);
                int p3 = atomicAdd(&lh[dv.w >> 6], 1);
                bedge[base + p0] = ((unsigned)sv.x << 6) | (unsigned)(dv.x & 63);
                bedge[base + p1] = ((unsigned)sv.y << 6) | (unsigned)(dv.y & 63);
                bedge[base + p2] = ((unsigned)sv.z << 6) | (unsigned)(dv.z & 63);
                bedge[base + p3] = ((unsigned)sv.w << 6) | (unsigned)(dv.w & 63);
            } else {
                for (int jj = elem; jj < e && jj < elem + 4; ++jj) {
                    int pos = atomicAdd(&lh[dst[jj] >> 6], 1);
                    bedge[base + pos] = ((unsigned)src[jj] << 6) | (unsigned)(dst[jj] & 63);
                }
            }
        }
    }
}

// load per-bucket run table + prefix; returns cnt. 512 threads.
__device__ __forceinline__ int load_runs(const int* __restrict__ loffT, int b,
                                         int B, int* runstart, int* runoff,
                                         int* sm) {
    int tid = threadIdx.x;
    if (tid < 256) {
        int len = 0, st = 0;
        if (tid < B) {
            int lo = loffT[(size_t)b * B + tid];
            int hi = loffT[(size_t)(b + 1) * B + tid];
            st = tid * EPB + lo;
            len = hi - lo;
        }
        runstart[tid] = st;
        sm[tid] = len;
    }
    __syncthreads();
    for (int off = 1; off < 256; off <<= 1) {
        int u = (tid < 256 && tid >= off) ? sm[tid - off] : 0;
        __syncthreads();
        if (tid < 256) sm[tid] += u;
        __syncthreads();
    }
    if (tid < 256) runoff[tid + 1] = sm[tid];
    if (tid == 0) runoff[0] = 0;
    __syncthreads();
    return runoff[256];
}

__device__ __forceinline__ int find_run(const int* runoff, int i) {
    int lo = 0, hi = 256;
    #pragma unroll
    for (int it = 0; it < 8; ++it) {
        int mid = (lo + hi) >> 1;
        if (runoff[mid] <= i) lo = mid; else hi = mid;
    }
    return lo;
}

// ---- K2: per-bucket: stage via run binary-search -> rank -> float4 pull of xn
//      -> h = relu(xs + mean + b1). Emits ranked fsrc[b*CAP+..] + lofsG.
__global__ void __launch_bounds__(512)
k_agg1(const unsigned* __restrict__ bedge, const int* __restrict__ loffT,
       const float* __restrict__ xs, const float* __restrict__ xn,
       const float* __restrict__ b1, float* __restrict__ h,
       int* __restrict__ fsrc, int* __restrict__ lofsG, int n, int B) {
    __shared__ int runstart[256];
    __shared__ int runoff[257];
    __shared__ int sm[256];
    __shared__ int ltmp[CAP];
    __shared__ int lsrc[CAP];
    __shared__ int lcnt[BK];
    __shared__ int lofs[BK + 1];
    __shared__ int lcur[BK];
    __shared__ float facc[BK][HID];
    int tid = threadIdx.x, b = blockIdx.x;
    int cnt = load_runs(loffT, b, B, runstart, runoff, sm);
    bool fits = (cnt <= CAP);
    if (tid < BK) lcnt[tid] = 0;
    __syncthreads();
    int node0 = b * BK;
    if (fits) {
        for (int i = tid; i < cnt; i += 512) {
            int rb = find_run(runoff, i);
            int p = (int)bedge[runstart[rb] + (i - runoff[rb])];
            ltmp[i] = p;
            atomicAdd(&lcnt[p & 63], 1);
        }
        __syncthreads();
        if (tid < BK) {
            int v = lcnt[tid];
            #pragma unroll
            for (int off = 1; off < 64; off <<= 1) {
                int t = __shfl_up(v, off);
                if (tid >= off) v += t;
            }
            lofs[tid + 1] = v;
            if (tid == 0) lofs[0] = 0;
            lcur[tid] = lofs[tid];
        }
        __syncthreads();
        for (int i = tid; i < cnt; i += 512) {
            int p = ltmp[i];
            int r = atomicAdd(&lcur[p & 63], 1);
            lsrc[r] = p >> 6;
        }
        __syncthreads();
        // export ranked CSR for K3
        if (tid <= BK) lofsG[(size_t)b * (BK + 1) + tid] = lofs[tid];
        for (int i = tid; i < cnt; i += 512) fsrc[(size_t)b * CAP + i] = lsrc[i];
        // float4 pull: tid = nl*8 + half*4 + d4
        int d4 = tid & 3;
        int half = (tid >> 2) & 1;
        int nl = tid >> 3;
        int node = node0 + nl;
        int t0 = lofs[nl], t1 = lofs[nl + 1];
        const float4* xn4 = (const float4*)xn;
        float4 a0 = make_float4(0.f, 0.f, 0.f, 0.f);
        float4 a1 = make_float4(0.f, 0.f, 0.f, 0.f);
        int k = t0 + half;
        for (; k + 2 < t1; k += 4) {
            f4add(a0, xn4[(size_t)lsrc[k] * 4 + d4]);
            f4add(a1, xn4[(size_t)lsrc[k + 2] * 4 + d4]);
        }
        if (k < t1) f4add(a0, xn4[(size_t)lsrc[k] * 4 + d4]);
        f4add(a0, a1);
        a0.x += __shfl_xor(a0.x, 4);
        a0.y += __shfl_xor(a0.y, 4);
        a0.z += __shfl_xor(a0.z, 4);
        a0.w += __shfl_xor(a0.w, 4);
        if (half == 0 && node < n) {
            float inv = 1.0f / fmaxf((float)(t1 - t0), 1.0f);
            float4 xv = ((const float4*)xs)[(size_t)node * 4 + d4];
            float4 bv = ((const float4*)b1)[d4];
            float4 hv;
            hv.x = fmaxf(xv.x + a0.x * inv + bv.x, 0.f);
            hv.y = fmaxf(xv.y + a0.y * inv + bv.y, 0.f);
            hv.z = fmaxf(xv.z + a0.z * inv + bv.z, 0.f);
            hv.w = fmaxf(xv.w + a0.w * inv + bv.w, 0.f);
            ((float4*)h)[(size_t)node * 4 + d4] = hv;
        }
    } else {
        // slow path (cnt > CAP; ~never for uniform dst): LDS-atomic accumulate
        for (int i = tid; i < BK * HID; i += 512) ((float*)facc)[i] = 0.f;
        __syncthreads();
        for (long long idx = tid; idx < (long long)cnt * HID; idx += 512) {
            int i = (int)(idx >> 4), d = (int)(idx & 15);
            int rb = find_run(runoff, i);
            int p = (int)bedge[runstart[rb] + (i - runoff[rb])];
            atomicAdd(&facc[p & 63][d], xn[(size_t)(p >> 6) * HID + d]);
            if (d == 0) atomicAdd(&lcnt[p & 63], 1);
        }
        __syncthreads();
        if (tid < BK) {
            int v = lcnt[tid];
            #pragma unroll
            for (int off = 1; off < 64; off <<= 1) {
                int t = __shfl_up(v, off);
                if (tid >= off) v += t;
            }
            lofs[tid + 1] = v;
            if (tid == 0) lofs[0] = 0;
        }
        __syncthreads();
        if (tid <= BK) lofsG[(size_t)b * (BK + 1) + tid] = lofs[tid];
        for (int i = tid; i < BK * HID; i += 512) {
            int nl = i >> 4, d = i & 15;
            int node = node0 + nl;
            if (node < n) {
                float dg = fmaxf((float)lcnt[nl], 1.0f);
                float v = xs[(size_t)node * HID + d] + facc[nl][d] / dg + b1[d];
                h[(size_t)node * HID + d] = fmaxf(v, 0.f);
            }
        }
    }
}

// ---- K3: per-bucket float4 pull of h (from ranked fsrc) + fused output GEMM.
__global__ void __launch_bounds__(512)
k_agg2_out(const unsigned* __restrict__ bedge, const int* __restrict__ loffT,
           const int* __restrict__ fsrc, const int* __restrict__ lofsG,
           const float* __restrict__ h,
           const float* __restrict__ Ws2, const float* __restrict__ Wn2,
           const float* __restrict__ b2, float* __restrict__ out, int n, int B) {
    __shared__ int   runstart[256];
    __shared__ int   runoff[257];
    __shared__ int   smi[256];
    __shared__ int   lidx[CAP];
    __shared__ int   lofs[BK + 1];
    __shared__ float lh[BK][HID];
    __shared__ float lagg[BK][HID];
    __shared__ float lws[HID][OUT];
    __shared__ float lwn[HID][OUT];
    __shared__ float lb2v[OUT];
    int tid = threadIdx.x, b = blockIdx.x;
    int node0 = b * BK;
    if (tid <= BK) lofs[tid] = lofsG[(size_t)b * (BK + 1) + tid];
    for (int i = tid; i < BK * HID; i += 512) {
        int node = node0 + (i >> 4);
        lh[i >> 4][i & 15] = (node < n) ? h[(size_t)node * HID + (i & 15)] : 0.f;
    }
    for (int i = tid; i < HID * OUT; i += 512) {
        ((float*)lws)[i] = Ws2[i];
        ((float*)lwn)[i] = Wn2[i];
    }
    if (tid < OUT) lb2v[tid] = b2[tid];
    __syncthreads();
    int cnt = lofs[BK];
    bool fits = (cnt <= CAP);
    if (fits) {
        for (int i = tid; i < cnt; i += 512) lidx[i] = fsrc[(size_t)b * CAP + i];
        __syncthreads();
        int d4 = tid & 3;
        int half = (tid >> 2) & 1;
        int nl = tid >> 3;
        int t0 = lofs[nl], t1 = lofs[nl + 1];
        const float4* h4 = (const float4*)h;
        float4 a0 = make_float4(0.f, 0.f, 0.f, 0.f);
        float4 a1 = make_float4(0.f, 0.f, 0.f, 0.f);
        int k = t0 + half;
        for (; k + 2 < t1; k += 4) {
            f4add(a0, h4[(size_t)lidx[k] * 4 + d4]);
            f4add(a1, h4[(size_t)lidx[k + 2] * 4 + d4]);
        }
        if (k < t1) f4add(a0, h4[(size_t)lidx[k] * 4 + d4]);
        f4add(a0, a1);
        a0.x += __shfl_xor(a0.x, 4);
        a0.y += __shfl_xor(a0.y, 4);
        a0.z += __shfl_xor(a0.z, 4);
        a0.w += __shfl_xor(a0.w, 4);
        if (half == 0) {
            float inv = 1.0f / fmaxf((float)(t1 - t0), 1.0f);
            float4 r;
            r.x = a0.x * inv; r.y = a0.y * inv; r.z = a0.z * inv; r.w = a0.w * inv;
            *(float4*)&lagg[nl][d4 * 4] = r;
        }
    } else {
        // slow path: accumulate from bedge runs
        int cnt2 = load_runs(loffT, b, B, runstart, runoff, smi);
        for (int i = tid; i < BK * HID; i += 512) ((float*)lagg)[i] = 0.f;
        __syncthreads();
        for (long long idx = tid; idx < (long long)cnt2 * HID; idx += 512) {
            int i = (int)(idx >> 4), d = (int)(idx & 15);
            int rb = find_run(runoff, i);
            int p = (int)bedge[runstart[rb] + (i - runoff[rb])];
            atomicAdd(&lagg[p & 63][d], h[(size_t)(p >> 6) * HID + d]);
        }
        __syncthreads();
        for (int i = tid; i < BK * HID; i += 512) {
            int nl = i >> 4, d = i & 15;
            float dg = fmaxf((float)(lofs[nl + 1] - lofs[nl]), 1.0f);
            if (d == 0) {}
            lagg[nl][d] /= dg;
        }
    }
    __syncthreads();
    for (int i = tid; i < BK * OUT; i += 512) {
        int nl2 = i >> 6, o = i & 63;
        int node = node0 + nl2;
        if (node >= n) continue;
        float acm = lb2v[o];
        #pragma unroll
        for (int j = 0; j < HID; ++j)
            acm += lh[nl2][j] * lws[j][o] + lagg[nl2][j] * lwn[j][o];
        out[(size_t)node * OUT + o] = acm;
    }
}

extern "C" void kernel_launch(void* const* d_in, const int* in_sizes, int n_in,
                              void* d_out, int out_size, void* d_ws, size_t ws_size,
                              hipStream_t stream) {
    const float* x   = (const float*)d_in[0];
    const int*   src = (const int*)d_in[1];
    const int*   dst = (const int*)d_in[2];
    const float* Ws1 = (const float*)d_in[3];
    const float* Wn1 = (const float*)d_in[4];
    const float* b1  = (const float*)d_in[5];
    const float* Ws2 = (const float*)d_in[6];
    const float* Wn2 = (const float*)d_in[7];
    const float* b2  = (const float*)d_in[8];
    float* out = (float*)d_out;

    int n = in_sizes[0] / IN;          // 50000
    int e = in_sizes[1];               // 800000
    int K = (n + BK - 1) / BK;         // 782 buckets
    int B = (e + EPB - 1) / EPB;       // 196 partition blocks (<=256)
    int nproj = (n + 7) / 8;           // 6250 proj blocks

    // ws: loffT[(K+1)*B] | bedge[B*EPB] | fsrc[K*CAP] | lofsG[K*(BK+1)] | xs | xn | h
    int* loffT = (int*)d_ws;
    unsigned* bedge = (unsigned*)(loffT + (size_t)(K + 1) * B);
    int* fsrc  = (int*)(bedge + (size_t)B * EPB);
    int* lofsG = fsrc + (size_t)K * CAP;
    float* xs = (float*)(lofsG + (size_t)K * (BK + 1));
    float* xn = xs + (size_t)n * HID;
    float* h  = xn + (size_t)n * HID;

    k_proj_part<<<nproj + B, 256, 0, stream>>>(x, Ws1, Wn1, src, dst, xs, xn,
                                               loffT, bedge, n, e, nproj, K, B);
    k_agg1<<<K, 512, 0, stream>>>(bedge, loffT, xs, xn, b1, h, fsrc, lofsG, n, B);
    k_agg2_out<<<K, 512, 0, stream>>>(bedge, loffT, fsrc, lofsG, h,
                                      Ws2, Wn2, b2, out, n, B);
}

// Round 17
// 64.114 us; speedup vs baseline: 2.5996x; 1.1598x over previous
//
#include <hip/hip_runtime.h>

#define IN   128
#define HID  16
#define OUT  64
#define BK   64        // nodes per bucket (bucket = dst >> 6)
#define EPB  4096      // edges per partition block (B=196 blocks)
#define CAP  2048      // staging capacity per bucket (mean ~1024, 30-sigma safe)
#define PBN  16        // nodes per proj block (2 per thread)

__device__ __forceinline__ void f4add(float4& a, const float4 v) {
    a.x += v.x; a.y += v.y; a.z += v.z; a.w += v.w;
}

// ---- K1 (fused): blocks [0,B) = block-local partition (FIRST: heavy blocks
//      overlap under the proj wave instead of forming the tail).
//      Blocks [B, B+nproj) = proj, 16 nodes/block, 2 nodes/thread so each
//      weight-row LDS read is reused twice (halves non-broadcast LDS traffic).
__global__ void __launch_bounds__(256)
k_proj_part(const float* __restrict__ x,
            const float* __restrict__ Ws,
            const float* __restrict__ Wn,
            const int* __restrict__ src,
            const int* __restrict__ dst,
            float* __restrict__ xs,
            float* __restrict__ xn,
            int* __restrict__ loffT,
            unsigned* __restrict__ bedge,
            int n, int e, int K, int B) {
    __shared__ __align__(16) float smem[4224 + 2048];  // lwT[32][132] + lx[16][128]
    int tid = threadIdx.x;   // 256
    if ((int)blockIdx.x < B) {
        // ---- partition block (R16-proven body) ----
        int* ism = (int*)smem;
        int* lh  = ism;            // [1024] counts, later cursors
        int* lsc = ism + 1024;     // [K+1] exclusive scan
        int* sm  = ism + 2050;     // [256] scan temp
        int blk = blockIdx.x;
        for (int i = tid; i < K; i += 256) lh[i] = 0;
        __syncthreads();
        const int4* d4 = (const int4*)dst;
        #pragma unroll
        for (int it = 0; it < EPB / 1024; ++it) {
            int i4 = blk * (EPB / 4) + it * 256 + tid;
            int elem = i4 * 4;
            if (elem + 3 < e) {
                int4 v = d4[i4];
                atomicAdd(&lh[v.x >> 6], 1);
                atomicAdd(&lh[v.y >> 6], 1);
                atomicAdd(&lh[v.z >> 6], 1);
                atomicAdd(&lh[v.w >> 6], 1);
            } else {
                for (int jj = elem; jj < e && jj < elem + 4; ++jj)
                    atomicAdd(&lh[dst[jj] >> 6], 1);
            }
        }
        __syncthreads();
        int C = (K + 255) >> 8;
        int i0 = tid * C, i1 = min(i0 + C, K);
        int s = 0;
        for (int i = i0; i < i1; ++i) s += lh[i];
        sm[tid] = s;
        __syncthreads();
        for (int off = 1; off < 256; off <<= 1) {
            int u = (tid >= off) ? sm[tid - off] : 0;
            __syncthreads();
            sm[tid] += u;
            __syncthreads();
        }
        int run = sm[tid] - s;
        for (int i = i0; i < i1; ++i) {
            int vv = lh[i];
            lsc[i] = run;
            run += vv;
        }
        if (tid == 255) lsc[K] = sm[255];
        __syncthreads();
        for (int bb = tid; bb <= K; bb += 256)
            loffT[(size_t)bb * B + blk] = lsc[bb];
        for (int bb = tid; bb < K; bb += 256) lh[bb] = lsc[bb];  // cursors
        __syncthreads();
        unsigned base = (unsigned)blk * EPB;
        const int4* s4 = (const int4*)src;
        #pragma unroll
        for (int it = 0; it < EPB / 1024; ++it) {
            int i4 = blk * (EPB / 4) + it * 256 + tid;
            int elem = i4 * 4;
            if (elem + 3 < e) {
                int4 sv = s4[i4];
                int4 dv = d4[i4];
                int p0 = atomicAdd(&lh[dv.x >> 6], 1);
                int p1 = atomicAdd(&lh[dv.y >> 6], 1);
                int p2 = atomicAdd(&lh[dv.z >> 6], 1);
                int p3 = atomicAdd(&lh[dv.w >> 6], 1);
                bedge[base + p0] = ((unsigned)sv.x << 6) | (unsigned)(dv.x & 63);
                bedge[base + p1] = ((unsigned)sv.y << 6) | (unsigned)(dv.y & 63);
                bedge[base + p2] = ((unsigned)sv.z << 6) | (unsigned)(dv.z & 63);
                bedge[base + p3] = ((unsigned)sv.w << 6) | (unsigned)(dv.w & 63);
            } else {
                for (int jj = elem; jj < e && jj < elem + 4; ++jj) {
                    int pos = atomicAdd(&lh[dst[jj] >> 6], 1);
                    bedge[base + pos] = ((unsigned)src[jj] << 6) | (unsigned)(dst[jj] & 63);
                }
            }
        }
    } else {
        // ---- proj block: 16 nodes, 2 per thread ----
        float (*lwT)[132] = (float (*)[132])smem;          // [32][132]
        float (*lx)[IN]   = (float (*)[IN])(smem + 4224);  // [16][128]
        for (int i = tid; i < IN * 32; i += 256) {
            int k = i >> 5, j = i & 31;
            lwT[j][k] = (j < HID) ? Ws[k * HID + j] : Wn[k * HID + (j - 16)];
        }
        int node0 = (blockIdx.x - B) * PBN;
        const float4* x4 = (const float4*)x;
        float4* lx4 = (float4*)lx;     // [16][32] float4 = 512
        #pragma unroll
        for (int q = 0; q < 2; ++q) {
            int i = q * 256 + tid;
            int r = i >> 5, c4 = i & 31;
            int node = node0 + r;
            lx4[i] = (node < n) ? x4[(size_t)node * 32 + c4]
                                : make_float4(0.f, 0.f, 0.f, 0.f);
        }
        __syncthreads();
        int r0 = tid >> 5, j = tid & 31;
        const float4* lxr0 = (const float4*)lx[r0];
        const float4* lxr1 = (const float4*)lx[r0 + 8];
        float acc0 = 0.f, acc1 = 0.f;
        #pragma unroll 4
        for (int k4 = 0; k4 < 32; ++k4) {
            float4 wv = *(const float4*)&lwT[j][k4 * 4];
            float4 x0 = lxr0[k4];
            float4 x1 = lxr1[k4];
            acc0 += x0.x * wv.x + x0.y * wv.y + x0.z * wv.z + x0.w * wv.w;
            acc1 += x1.x * wv.x + x1.y * wv.y + x1.z * wv.z + x1.w * wv.w;
        }
        int nodeA = node0 + r0;
        int nodeB = node0 + r0 + 8;
        if (nodeA < n) {
            if (j < HID) xs[(size_t)nodeA * HID + j] = acc0;
            else         xn[(size_t)nodeA * HID + (j - 16)] = acc0;
        }
        if (nodeB < n) {
            if (j < HID) xs[(size_t)nodeB * HID + j] = acc1;
            else         xn[(size_t)nodeB * HID + (j - 16)] = acc1;
        }
    }
}

// load per-bucket run table + prefix; returns cnt. 512 threads.
__device__ __forceinline__ int load_runs(const int* __restrict__ loffT, int b,
                                         int B, int* runstart, int* runoff,
                                         int* sm) {
    int tid = threadIdx.x;
    if (tid < 256) {
        int len = 0, st = 0;
        if (tid < B) {
            int lo = loffT[(size_t)b * B + tid];
            int hi = loffT[(size_t)(b + 1) * B + tid];
            st = tid * EPB + lo;
            len = hi - lo;
        }
        runstart[tid] = st;
        sm[tid] = len;
    }
    __syncthreads();
    for (int off = 1; off < 256; off <<= 1) {
        int u = (tid < 256 && tid >= off) ? sm[tid - off] : 0;
        __syncthreads();
        if (tid < 256) sm[tid] += u;
        __syncthreads();
    }
    if (tid < 256) runoff[tid + 1] = sm[tid];
    if (tid == 0) runoff[0] = 0;
    __syncthreads();
    return runoff[256];
}

__device__ __forceinline__ int find_run(const int* runoff, int i) {
    int lo = 0, hi = 256;
    #pragma unroll
    for (int it = 0; it < 8; ++it) {
        int mid = (lo + hi) >> 1;
        if (runoff[mid] <= i) lo = mid; else hi = mid;
    }
    return lo;
}

// ---- K2: per-bucket: stage via run binary-search -> rank -> float4 pull of xn
//      -> h = relu(xs + mean + b1). Emits ranked fsrc[b*CAP+..] + lofsG.
__global__ void __launch_bounds__(512)
k_agg1(const unsigned* __restrict__ bedge, const int* __restrict__ loffT,
       const float* __restrict__ xs, const float* __restrict__ xn,
       const float* __restrict__ b1, float* __restrict__ h,
       int* __restrict__ fsrc, int* __restrict__ lofsG, int n, int B) {
    __shared__ int runstart[256];
    __shared__ int runoff[257];
    __shared__ int sm[256];
    __shared__ int ltmp[CAP];
    __shared__ int lsrc[CAP];
    __shared__ int lcnt[BK];
    __shared__ int lofs[BK + 1];
    __shared__ int lcur[BK];
    __shared__ float facc[BK][HID];
    int tid = threadIdx.x, b = blockIdx.x;
    int cnt = load_runs(loffT, b, B, runstart, runoff, sm);
    bool fits = (cnt <= CAP);
    if (tid < BK) lcnt[tid] = 0;
    __syncthreads();
    int node0 = b * BK;
    if (fits) {
        for (int i = tid; i < cnt; i += 512) {
            int rb = find_run(runoff, i);
            int p = (int)bedge[runstart[rb] + (i - runoff[rb])];
            ltmp[i] = p;
            atomicAdd(&lcnt[p & 63], 1);
        }
        __syncthreads();
        if (tid < BK) {
            int v = lcnt[tid];
            #pragma unroll
            for (int off = 1; off < 64; off <<= 1) {
                int t = __shfl_up(v, off);
                if (tid >= off) v += t;
            }
            lofs[tid + 1] = v;
            if (tid == 0) lofs[0] = 0;
            lcur[tid] = lofs[tid];
        }
        __syncthreads();
        for (int i = tid; i < cnt; i += 512) {
            int p = ltmp[i];
            int r = atomicAdd(&lcur[p & 63], 1);
            lsrc[r] = p >> 6;
        }
        __syncthreads();
        if (tid <= BK) lofsG[(size_t)b * (BK + 1) + tid] = lofs[tid];
        for (int i = tid; i < cnt; i += 512) fsrc[(size_t)b * CAP + i] = lsrc[i];
        int d4 = tid & 3;
        int half = (tid >> 2) & 1;
        int nl = tid >> 3;
        int node = node0 + nl;
        int t0 = lofs[nl], t1 = lofs[nl + 1];
        const float4* xn4 = (const float4*)xn;
        float4 a0 = make_float4(0.f, 0.f, 0.f, 0.f);
        float4 a1 = make_float4(0.f, 0.f, 0.f, 0.f);
        int k = t0 + half;
        for (; k + 2 < t1; k += 4) {
            f4add(a0, xn4[(size_t)lsrc[k] * 4 + d4]);
            f4add(a1, xn4[(size_t)lsrc[k + 2] * 4 + d4]);
        }
        if (k < t1) f4add(a0, xn4[(size_t)lsrc[k] * 4 + d4]);
        f4add(a0, a1);
        a0.x += __shfl_xor(a0.x, 4);
        a0.y += __shfl_xor(a0.y, 4);
        a0.z += __shfl_xor(a0.z, 4);
        a0.w += __shfl_xor(a0.w, 4);
        if (half == 0 && node < n) {
            float inv = 1.0f / fmaxf((float)(t1 - t0), 1.0f);
            float4 xv = ((const float4*)xs)[(size_t)node * 4 + d4];
            float4 bv = ((const float4*)b1)[d4];
            float4 hv;
            hv.x = fmaxf(xv.x + a0.x * inv + bv.x, 0.f);
            hv.y = fmaxf(xv.y + a0.y * inv + bv.y, 0.f);
            hv.z = fmaxf(xv.z + a0.z * inv + bv.z, 0.f);
            hv.w = fmaxf(xv.w + a0.w * inv + bv.w, 0.f);
            ((float4*)h)[(size_t)node * 4 + d4] = hv;
        }
    } else {
        for (int i = tid; i < BK * HID; i += 512) ((float*)facc)[i] = 0.f;
        __syncthreads();
        for (long long idx = tid; idx < (long long)cnt * HID; idx += 512) {
            int i = (int)(idx >> 4), d = (int)(idx & 15);
            int rb = find_run(runoff, i);
            int p = (int)bedge[runstart[rb] + (i - runoff[rb])];
            atomicAdd(&facc[p & 63][d], xn[(size_t)(p >> 6) * HID + d]);
            if (d == 0) atomicAdd(&lcnt[p & 63], 1);
        }
        __syncthreads();
        if (tid < BK) {
            int v = lcnt[tid];
            #pragma unroll
            for (int off = 1; off < 64; off <<= 1) {
                int t = __shfl_up(v, off);
                if (tid >= off) v += t;
            }
            lofs[tid + 1] = v;
            if (tid == 0) lofs[0] = 0;
        }
        __syncthreads();
        if (tid <= BK) lofsG[(size_t)b * (BK + 1) + tid] = lofs[tid];
        for (int i = tid; i < BK * HID; i += 512) {
            int nl = i >> 4, d = i & 15;
            int node = node0 + nl;
            if (node < n) {
                float dg = fmaxf((float)lcnt[nl], 1.0f);
                float v = xs[(size_t)node * HID + d] + facc[nl][d] / dg + b1[d];
                h[(size_t)node * HID + d] = fmaxf(v, 0.f);
            }
        }
    }
}

// ---- K3: per-bucket float4 pull of h (from ranked fsrc) + fused output GEMM.
__global__ void __launch_bounds__(512)
k_agg2_out(const unsigned* __restrict__ bedge, const int* __restrict__ loffT,
           const int* __restrict__ fsrc, const int* __restrict__ lofsG,
           const float* __restrict__ h,
           const float* __restrict__ Ws2, const float* __restrict__ Wn2,
           const float* __restrict__ b2, float* __restrict__ out, int n, int B) {
    __shared__ int   runstart[256];
    __shared__ int   runoff[257];
    __shared__ int   smi[256];
    __shared__ int   lidx[CAP];
    __shared__ int   lofs[BK + 1];
    __shared__ float lh[BK][HID];
    __shared__ float lagg[BK][HID];
    __shared__ float lws[HID][OUT];
    __shared__ float lwn[HID][OUT];
    __shared__ float lb2v[OUT];
    int tid = threadIdx.x, b = blockIdx.x;
    int node0 = b * BK;
    if (tid <= BK) lofs[tid] = lofsG[(size_t)b * (BK + 1) + tid];
    for (int i = tid; i < BK * HID; i += 512) {
        int node = node0 + (i >> 4);
        lh[i >> 4][i & 15] = (node < n) ? h[(size_t)node * HID + (i & 15)] : 0.f;
    }
    for (int i = tid; i < HID * OUT; i += 512) {
        ((float*)lws)[i] = Ws2[i];
        ((float*)lwn)[i] = Wn2[i];
    }
    if (tid < OUT) lb2v[tid] = b2[tid];
    __syncthreads();
    int cnt = lofs[BK];
    bool fits = (cnt <= CAP);
    if (fits) {
        for (int i = tid; i < cnt; i += 512) lidx[i] = fsrc[(size_t)b * CAP + i];
        __syncthreads();
        int d4 = tid & 3;
        int half = (tid >> 2) & 1;
        int nl = tid >> 3;
        int t0 = lofs[nl], t1 = lofs[nl + 1];
        const float4* h4 = (const float4*)h;
        float4 a0 = make_float4(0.f, 0.f, 0.f, 0.f);
        float4 a1 = make_float4(0.f, 0.f, 0.f, 0.f);
        int k = t0 + half;
        for (; k + 2 < t1; k += 4) {
            f4add(a0, h4[(size_t)lidx[k] * 4 + d4]);
            f4add(a1, h4[(size_t)lidx[k + 2] * 4 + d4]);
        }
        if (k < t1) f4add(a0, h4[(size_t)lidx[k] * 4 + d4]);
        f4add(a0, a1);
        a0.x += __shfl_xor(a0.x, 4);
        a0.y += __shfl_xor(a0.y, 4);
        a0.z += __shfl_xor(a0.z, 4);
        a0.w += __shfl_xor(a0.w, 4);
        if (half == 0) {
            float inv = 1.0f / fmaxf((float)(t1 - t0), 1.0f);
            float4 r;
            r.x = a0.x * inv; r.y = a0.y * inv; r.z = a0.z * inv; r.w = a0.w * inv;
            *(float4*)&lagg[nl][d4 * 4] = r;
        }
    } else {
        int cnt2 = load_runs(loffT, b, B, runstart, runoff, smi);
        for (int i = tid; i < BK * HID; i += 512) ((float*)lagg)[i] = 0.f;
        __syncthreads();
        for (long long idx = tid; idx < (long long)cnt2 * HID; idx += 512) {
            int i = (int)(idx >> 4), d = (int)(idx & 15);
            int rb = find_run(runoff, i);
            int p = (int)bedge[runstart[rb] + (i - runoff[rb])];
            atomicAdd(&lagg[p & 63][d], h[(size_t)(p >> 6) * HID + d]);
        }
        __syncthreads();
        for (int i = tid; i < BK * HID; i += 512) {
            int nl = i >> 4, d = i & 15;
            float dg = fmaxf((float)(lofs[nl + 1] - lofs[nl]), 1.0f);
            lagg[nl][d] /= dg;
        }
    }
    __syncthreads();
    for (int i = tid; i < BK * OUT; i += 512) {
        int nl2 = i >> 6, o = i & 63;
        int node = node0 + nl2;
        if (node >= n) continue;
        float acm = lb2v[o];
        #pragma unroll
        for (int j = 0; j < HID; ++j)
            acm += lh[nl2][j] * lws[j][o] + lagg[nl2][j] * lwn[j][o];
        out[(size_t)node * OUT + o] = acm;
    }
}

extern "C" void kernel_launch(void* const* d_in, const int* in_sizes, int n_in,
                              void* d_out, int out_size, void* d_ws, size_t ws_size,
                              hipStream_t stream) {
    const float* x   = (const float*)d_in[0];
    const int*   src = (const int*)d_in[1];
    const int*   dst = (const int*)d_in[2];
    const float* Ws1 = (const float*)d_in[3];
    const float* Wn1 = (const float*)d_in[4];
    const float* b1  = (const float*)d_in[5];
    const float* Ws2 = (const float*)d_in[6];
    const float* Wn2 = (const float*)d_in[7];
    const float* b2  = (const float*)d_in[8];
    float* out = (float*)d_out;

    int n = in_sizes[0] / IN;          // 50000
    int e = in_sizes[1];               // 800000
    int K = (n + BK - 1) / BK;         // 782 buckets
    int B = (e + EPB - 1) / EPB;       // 196 partition blocks (<=256)
    int nproj = (n + PBN - 1) / PBN;   // 3125 proj blocks

    // ws: loffT[(K+1)*B] | bedge[B*EPB] | fsrc[K*CAP] | lofsG[K*(BK+1)] | xs | xn | h
    int* loffT = (int*)d_ws;
    unsigned* bedge = (unsigned*)(loffT + (size_t)(K + 1) * B);
    int* fsrc  = (int*)(bedge + (size_t)B * EPB);
    int* lofsG = fsrc + (size_t)K * CAP;
    float* xs = (float*)(lofsG + (size_t)K * (BK + 1));
    float* xn = xs + (size_t)n * HID;
    float* h  = xn + (size_t)n * HID;

    k_proj_part<<<B + nproj, 256, 0, stream>>>(x, Ws1, Wn1, src, dst, xs, xn,
                                               loffT, bedge, n, e, K, B);
    k_agg1<<<K, 512, 0, stream>>>(bedge, loffT, xs, xn, b1, h, fsrc, lofsG, n, B);
    k_agg2_out<<<K, 512, 0, stream>>>(bedge, loffT, fsrc, lofsG, h,
                                      Ws2, Wn2, b2, out, n, B);
}

// Round 18
// 58.571 us; speedup vs baseline: 2.8456x; 1.0946x over previous
//
#include <hip/hip_runtime.h>

#define IN   128
#define HID  16
#define OUT  64
#define BK   64        // nodes per bucket (bucket = dst >> 6)
#define EPB  4096      // edges per partition block (B=196 blocks)
#define CAP  2048      // staging capacity per bucket (mean ~1024, 30-sigma safe)
#define PBN  32        // nodes per proj block (4 per thread)

__device__ __forceinline__ void f4add(float4& a, const float4 v) {
    a.x += v.x; a.y += v.y; a.z += v.z; a.w += v.w;
}

// ---- K1 (fused): blocks [0,B) = block-local partition (first => overlapped).
//      Blocks [B, B+nproj) = proj, 32 nodes/block, 4 nodes/thread: each
//      weight-row LDS read reused 4x (x-row reads are half-wave broadcast).
__global__ void __launch_bounds__(256)
k_proj_part(const float* __restrict__ x,
            const float* __restrict__ Ws,
            const float* __restrict__ Wn,
            const int* __restrict__ src,
            const int* __restrict__ dst,
            float* __restrict__ xs,
            float* __restrict__ xn,
            int* __restrict__ loffT,
            unsigned* __restrict__ bedge,
            int n, int e, int K, int B) {
    __shared__ __align__(16) float smem[4224 + 4096];  // lwT[32][132] + lx[32][128]
    int tid = threadIdx.x;   // 256
    if ((int)blockIdx.x < B) {
        // ---- partition block (R16/R17-proven body) ----
        int* ism = (int*)smem;
        int* lh  = ism;            // [1024] counts, later cursors
        int* lsc = ism + 1024;     // [K+1]
        int* sm  = ism + 2050;     // [256]
        int blk = blockIdx.x;
        for (int i = tid; i < K; i += 256) lh[i] = 0;
        __syncthreads();
        const int4* d4 = (const int4*)dst;
        #pragma unroll
        for (int it = 0; it < EPB / 1024; ++it) {
            int i4 = blk * (EPB / 4) + it * 256 + tid;
            int elem = i4 * 4;
            if (elem + 3 < e) {
                int4 v = d4[i4];
                atomicAdd(&lh[v.x >> 6], 1);
                atomicAdd(&lh[v.y >> 6], 1);
                atomicAdd(&lh[v.z >> 6], 1);
                atomicAdd(&lh[v.w >> 6], 1);
            } else {
                for (int jj = elem; jj < e && jj < elem + 4; ++jj)
                    atomicAdd(&lh[dst[jj] >> 6], 1);
            }
        }
        __syncthreads();
        int C = (K + 255) >> 8;
        int i0 = tid * C, i1 = min(i0 + C, K);
        int s = 0;
        for (int i = i0; i < i1; ++i) s += lh[i];
        sm[tid] = s;
        __syncthreads();
        for (int off = 1; off < 256; off <<= 1) {
            int u = (tid >= off) ? sm[tid - off] : 0;
            __syncthreads();
            sm[tid] += u;
            __syncthreads();
        }
        int run = sm[tid] - s;
        for (int i = i0; i < i1; ++i) {
            int vv = lh[i];
            lsc[i] = run;
            run += vv;
        }
        if (tid == 255) lsc[K] = sm[255];
        __syncthreads();
        for (int bb = tid; bb <= K; bb += 256)
            loffT[(size_t)bb * B + blk] = lsc[bb];
        for (int bb = tid; bb < K; bb += 256) lh[bb] = lsc[bb];  // cursors
        __syncthreads();
        unsigned base = (unsigned)blk * EPB;
        const int4* s4 = (const int4*)src;
        #pragma unroll
        for (int it = 0; it < EPB / 1024; ++it) {
            int i4 = blk * (EPB / 4) + it * 256 + tid;
            int elem = i4 * 4;
            if (elem + 3 < e) {
                int4 sv = s4[i4];
                int4 dv = d4[i4];
                int p0 = atomicAdd(&lh[dv.x >> 6], 1);
                int p1 = atomicAdd(&lh[dv.y >> 6], 1);
                int p2 = atomicAdd(&lh[dv.z >> 6], 1);
                int p3 = atomicAdd(&lh[dv.w >> 6], 1);
                bedge[base + p0] = ((unsigned)sv.x << 6) | (unsigned)(dv.x & 63);
                bedge[base + p1] = ((unsigned)sv.y << 6) | (unsigned)(dv.y & 63);
                bedge[base + p2] = ((unsigned)sv.z << 6) | (unsigned)(dv.z & 63);
                bedge[base + p3] = ((unsigned)sv.w << 6) | (unsigned)(dv.w & 63);
            } else {
                for (int jj = elem; jj < e && jj < elem + 4; ++jj) {
                    int pos = atomicAdd(&lh[dst[jj] >> 6], 1);
                    bedge[base + pos] = ((unsigned)src[jj] << 6) | (unsigned)(dst[jj] & 63);
                }
            }
        }
    } else {
        // ---- proj block: 32 nodes, 4 per thread (rows r0, r0+8, r0+16, r0+24) ----
        float (*lwT)[132] = (float (*)[132])smem;          // [32][132]
        float (*lx)[IN]   = (float (*)[IN])(smem + 4224);  // [32][128]
        for (int i = tid; i < IN * 32; i += 256) {
            int k = i >> 5, j = i & 31;
            lwT[j][k] = (j < HID) ? Ws[k * HID + j] : Wn[k * HID + (j - 16)];
        }
        int node0 = (blockIdx.x - B) * PBN;
        const float4* x4 = (const float4*)x;
        float4* lx4 = (float4*)lx;     // [32][32] float4 = 1024
        #pragma unroll
        for (int q = 0; q < 4; ++q) {
            int i = q * 256 + tid;
            int r = i >> 5, c4 = i & 31;
            int node = node0 + r;
            lx4[i] = (node < n) ? x4[(size_t)node * 32 + c4]
                                : make_float4(0.f, 0.f, 0.f, 0.f);
        }
        __syncthreads();
        int r0 = tid >> 5, j = tid & 31;
        const float4* lxr0 = (const float4*)lx[r0];
        const float4* lxr1 = (const float4*)lx[r0 + 8];
        const float4* lxr2 = (const float4*)lx[r0 + 16];
        const float4* lxr3 = (const float4*)lx[r0 + 24];
        float acc0 = 0.f, acc1 = 0.f, acc2 = 0.f, acc3 = 0.f;
        #pragma unroll 4
        for (int k4 = 0; k4 < 32; ++k4) {
            float4 wv = *(const float4*)&lwT[j][k4 * 4];
            float4 x0 = lxr0[k4];
            float4 x1 = lxr1[k4];
            float4 x2 = lxr2[k4];
            float4 x3 = lxr3[k4];
            acc0 += x0.x * wv.x + x0.y * wv.y + x0.z * wv.z + x0.w * wv.w;
            acc1 += x1.x * wv.x + x1.y * wv.y + x1.z * wv.z + x1.w * wv.w;
            acc2 += x2.x * wv.x + x2.y * wv.y + x2.z * wv.z + x2.w * wv.w;
            acc3 += x3.x * wv.x + x3.y * wv.y + x3.z * wv.z + x3.w * wv.w;
        }
        float accs[4] = {acc0, acc1, acc2, acc3};
        #pragma unroll
        for (int q = 0; q < 4; ++q) {
            int node = node0 + r0 + q * 8;
            if (node < n) {
                if (j < HID) xs[(size_t)node * HID + j] = accs[q];
                else         xn[(size_t)node * HID + (j - 16)] = accs[q];
            }
        }
    }
}

// load per-bucket run table + prefix; returns cnt. 512 threads.
__device__ __forceinline__ int load_runs(const int* __restrict__ loffT, int b,
                                         int B, int* runstart, int* runoff,
                                         int* sm) {
    int tid = threadIdx.x;
    if (tid < 256) {
        int len = 0, st = 0;
        if (tid < B) {
            int lo = loffT[(size_t)b * B + tid];
            int hi = loffT[(size_t)(b + 1) * B + tid];
            st = tid * EPB + lo;
            len = hi - lo;
        }
        runstart[tid] = st;
        sm[tid] = len;
    }
    __syncthreads();
    for (int off = 1; off < 256; off <<= 1) {
        int u = (tid < 256 && tid >= off) ? sm[tid - off] : 0;
        __syncthreads();
        if (tid < 256) sm[tid] += u;
        __syncthreads();
    }
    if (tid < 256) runoff[tid + 1] = sm[tid];
    if (tid == 0) runoff[0] = 0;
    __syncthreads();
    return runoff[256];
}

__device__ __forceinline__ int find_run(const int* runoff, int i) {
    int lo = 0, hi = 256;
    #pragma unroll
    for (int it = 0; it < 8; ++it) {
        int mid = (lo + hi) >> 1;
        if (runoff[mid] <= i) lo = mid; else hi = mid;
    }
    return lo;
}

// ---- K2: per-bucket: stage via run binary-search -> rank -> float4 pull of xn
//      -> h = relu(xs + mean + b1). Emits ranked fsrc[b*CAP+..] + lofsG.
__global__ void __launch_bounds__(512)
k_agg1(const unsigned* __restrict__ bedge, const int* __restrict__ loffT,
       const float* __restrict__ xs, const float* __restrict__ xn,
       const float* __restrict__ b1, float* __restrict__ h,
       int* __restrict__ fsrc, int* __restrict__ lofsG, int n, int B) {
    __shared__ int runstart[256];
    __shared__ int runoff[257];
    __shared__ int sm[256];
    __shared__ int ltmp[CAP];
    __shared__ int lsrc[CAP];
    __shared__ int lcnt[BK];
    __shared__ int lofs[BK + 1];
    __shared__ int lcur[BK];
    __shared__ float facc[BK][HID];
    int tid = threadIdx.x, b = blockIdx.x;
    int cnt = load_runs(loffT, b, B, runstart, runoff, sm);
    bool fits = (cnt <= CAP);
    if (tid < BK) lcnt[tid] = 0;
    __syncthreads();
    int node0 = b * BK;
    if (fits) {
        for (int i = tid; i < cnt; i += 512) {
            int rb = find_run(runoff, i);
            int p = (int)bedge[runstart[rb] + (i - runoff[rb])];
            ltmp[i] = p;
            atomicAdd(&lcnt[p & 63], 1);
        }
        __syncthreads();
        if (tid < BK) {
            int v = lcnt[tid];
            #pragma unroll
            for (int off = 1; off < 64; off <<= 1) {
                int t = __shfl_up(v, off);
                if (tid >= off) v += t;
            }
            lofs[tid + 1] = v;
            if (tid == 0) lofs[0] = 0;
            lcur[tid] = lofs[tid];
        }
        __syncthreads();
        for (int i = tid; i < cnt; i += 512) {
            int p = ltmp[i];
            int r = atomicAdd(&lcur[p & 63], 1);
            lsrc[r] = p >> 6;
        }
        __syncthreads();
        if (tid <= BK) lofsG[(size_t)b * (BK + 1) + tid] = lofs[tid];
        for (int i = tid; i < cnt; i += 512) fsrc[(size_t)b * CAP + i] = lsrc[i];
        int d4 = tid & 3;
        int half = (tid >> 2) & 1;
        int nl = tid >> 3;
        int node = node0 + nl;
        int t0 = lofs[nl], t1 = lofs[nl + 1];
        const float4* xn4 = (const float4*)xn;
        float4 a0 = make_float4(0.f, 0.f, 0.f, 0.f);
        float4 a1 = make_float4(0.f, 0.f, 0.f, 0.f);
        int k = t0 + half;
        for (; k + 2 < t1; k += 4) {
            f4add(a0, xn4[(size_t)lsrc[k] * 4 + d4]);
            f4add(a1, xn4[(size_t)lsrc[k + 2] * 4 + d4]);
        }
        if (k < t1) f4add(a0, xn4[(size_t)lsrc[k] * 4 + d4]);
        f4add(a0, a1);
        a0.x += __shfl_xor(a0.x, 4);
        a0.y += __shfl_xor(a0.y, 4);
        a0.z += __shfl_xor(a0.z, 4);
        a0.w += __shfl_xor(a0.w, 4);
        if (half == 0 && node < n) {
            float inv = 1.0f / fmaxf((float)(t1 - t0), 1.0f);
            float4 xv = ((const float4*)xs)[(size_t)node * 4 + d4];
            float4 bv = ((const float4*)b1)[d4];
            float4 hv;
            hv.x = fmaxf(xv.x + a0.x * inv + bv.x, 0.f);
            hv.y = fmaxf(xv.y + a0.y * inv + bv.y, 0.f);
            hv.z = fmaxf(xv.z + a0.z * inv + bv.z, 0.f);
            hv.w = fmaxf(xv.w + a0.w * inv + bv.w, 0.f);
            ((float4*)h)[(size_t)node * 4 + d4] = hv;
        }
    } else {
        for (int i = tid; i < BK * HID; i += 512) ((float*)facc)[i] = 0.f;
        __syncthreads();
        for (long long idx = tid; idx < (long long)cnt * HID; idx += 512) {
            int i = (int)(idx >> 4), d = (int)(idx & 15);
            int rb = find_run(runoff, i);
            int p = (int)bedge[runstart[rb] + (i - runoff[rb])];
            atomicAdd(&facc[p & 63][d], xn[(size_t)(p >> 6) * HID + d]);
            if (d == 0) atomicAdd(&lcnt[p & 63], 1);
        }
        __syncthreads();
        if (tid < BK) {
            int v = lcnt[tid];
            #pragma unroll
            for (int off = 1; off < 64; off <<= 1) {
                int t = __shfl_up(v, off);
                if (tid >= off) v += t;
            }
            lofs[tid + 1] = v;
            if (tid == 0) lofs[0] = 0;
        }
        __syncthreads();
        if (tid <= BK) lofsG[(size_t)b * (BK + 1) + tid] = lofs[tid];
        for (int i = tid; i < BK * HID; i += 512) {
            int nl = i >> 4, d = i & 15;
            int node = node0 + nl;
            if (node < n) {
                float dg = fmaxf((float)lcnt[nl], 1.0f);
                float v = xs[(size_t)node * HID + d] + facc[nl][d] / dg + b1[d];
                h[(size_t)node * HID + d] = fmaxf(v, 0.f);
            }
        }
    }
}

// ---- K3: per-bucket float4 pull of h (ranked fsrc) + float4 output GEMM.
__global__ void __launch_bounds__(512)
k_agg2_out(const unsigned* __restrict__ bedge, const int* __restrict__ loffT,
           const int* __restrict__ fsrc, const int* __restrict__ lofsG,
           const float* __restrict__ h,
           const float* __restrict__ Ws2, const float* __restrict__ Wn2,
           const float* __restrict__ b2, float* __restrict__ out, int n, int B) {
    __shared__ int   runstart[256];
    __shared__ int   runoff[257];
    __shared__ int   smi[256];
    __shared__ int   lidx[CAP];
    __shared__ int   lofs[BK + 1];
    __shared__ float lh[BK][HID];
    __shared__ float lagg[BK][HID];
    __shared__ float lws[HID][OUT];
    __shared__ float lwn[HID][OUT];
    __shared__ float lb2v[OUT];
    int tid = threadIdx.x, b = blockIdx.x;
    int node0 = b * BK;
    if (tid <= BK) lofs[tid] = lofsG[(size_t)b * (BK + 1) + tid];
    for (int i = tid; i < BK * HID; i += 512) {
        int node = node0 + (i >> 4);
        lh[i >> 4][i & 15] = (node < n) ? h[(size_t)node * HID + (i & 15)] : 0.f;
    }
    for (int i = tid; i < HID * OUT; i += 512) {
        ((float*)lws)[i] = Ws2[i];
        ((float*)lwn)[i] = Wn2[i];
    }
    if (tid < OUT) lb2v[tid] = b2[tid];
    __syncthreads();
    int cnt = lofs[BK];
    bool fits = (cnt <= CAP);
    if (fits) {
        for (int i = tid; i < cnt; i += 512) lidx[i] = fsrc[(size_t)b * CAP + i];
        __syncthreads();
        int d4 = tid & 3;
        int half = (tid >> 2) & 1;
        int nl = tid >> 3;
        int t0 = lofs[nl], t1 = lofs[nl + 1];
        const float4* h4 = (const float4*)h;
        float4 a0 = make_float4(0.f, 0.f, 0.f, 0.f);
        float4 a1 = make_float4(0.f, 0.f, 0.f, 0.f);
        int k = t0 + half;
        for (; k + 2 < t1; k += 4) {
            f4add(a0, h4[(size_t)lidx[k] * 4 + d4]);
            f4add(a1, h4[(size_t)lidx[k + 2] * 4 + d4]);
        }
        if (k < t1) f4add(a0, h4[(size_t)lidx[k] * 4 + d4]);
        f4add(a0, a1);
        a0.x += __shfl_xor(a0.x, 4);
        a0.y += __shfl_xor(a0.y, 4);
        a0.z += __shfl_xor(a0.z, 4);
        a0.w += __shfl_xor(a0.w, 4);
        if (half == 0) {
            float inv = 1.0f / fmaxf((float)(t1 - t0), 1.0f);
            float4 r;
            r.x = a0.x * inv; r.y = a0.y * inv; r.z = a0.z * inv; r.w = a0.w * inv;
            *(float4*)&lagg[nl][d4 * 4] = r;
        }
    } else {
        int cnt2 = load_runs(loffT, b, B, runstart, runoff, smi);
        for (int i = tid; i < BK * HID; i += 512) ((float*)lagg)[i] = 0.f;
        __syncthreads();
        for (long long idx = tid; idx < (long long)cnt2 * HID; idx += 512) {
            int i = (int)(idx >> 4), d = (int)(idx & 15);
            int rb = find_run(runoff, i);
            int p = (int)bedge[runstart[rb] + (i - runoff[rb])];
            atomicAdd(&lagg[p & 63][d], h[(size_t)(p >> 6) * HID + d]);
        }
        __syncthreads();
        for (int i = tid; i < BK * HID; i += 512) {
            int nl = i >> 4, d = i & 15;
            float dg = fmaxf((float)(lofs[nl + 1] - lofs[nl]), 1.0f);
            lagg[nl][d] /= dg;
        }
    }
    __syncthreads();
    // float4 output GEMM: thread = (nl, o4); lws/lwn read as b128, out as float4
    for (int i = tid; i < BK * (OUT / 4); i += 512) {
        int nl2 = i >> 4, o4 = i & 15;
        int node = node0 + nl2;
        if (node >= n) continue;
        float4 acm = *(const float4*)&lb2v[o4 * 4];
        #pragma unroll
        for (int j = 0; j < HID; ++j) {
            float hj = lh[nl2][j];
            float aj = lagg[nl2][j];
            float4 ws4 = *(const float4*)&lws[j][o4 * 4];
            float4 wn4 = *(const float4*)&lwn[j][o4 * 4];
            acm.x += hj * ws4.x + aj * wn4.x;
            acm.y += hj * ws4.y + aj * wn4.y;
            acm.z += hj * ws4.z + aj * wn4.z;
            acm.w += hj * ws4.w + aj * wn4.w;
        }
        *(float4*)&out[(size_t)node * OUT + o4 * 4] = acm;
    }
}

extern "C" void kernel_launch(void* const* d_in, const int* in_sizes, int n_in,
                              void* d_out, int out_size, void* d_ws, size_t ws_size,
                              hipStream_t stream) {
    const float* x   = (const float*)d_in[0];
    const int*   src = (const int*)d_in[1];
    const int*   dst = (const int*)d_in[2];
    const float* Ws1 = (const float*)d_in[3];
    const float* Wn1 = (const float*)d_in[4];
    const float* b1  = (const float*)d_in[5];
    const float* Ws2 = (const float*)d_in[6];
    const float* Wn2 = (const float*)d_in[7];
    const float* b2  = (const float*)d_in[8];
    float* out = (float*)d_out;

    int n = in_sizes[0] / IN;          // 50000
    int e = in_sizes[1];               // 800000
    int K = (n + BK - 1) / BK;         // 782 buckets
    int B = (e + EPB - 1) / EPB;       // 196 partition blocks (<=256)
    int nproj = (n + PBN - 1) / PBN;   // 1563 proj blocks

    // ws: loffT[(K+1)*B] | bedge[B*EPB] | fsrc[K*CAP] | lofsG[K*(BK+1)] | xs | xn | h
    int* loffT = (int*)d_ws;
    unsigned* bedge = (unsigned*)(loffT + (size_t)(K + 1) * B);
    int* fsrc  = (int*)(bedge + (size_t)B * EPB);
    int* lofsG = fsrc + (size_t)K * CAP;
    float* xs = (float*)(lofsG + (size_t)K * (BK + 1));
    float* xn = xs + (size_t)n * HID;
    float* h  = xn + (size_t)n * HID;

    k_proj_part<<<B + nproj, 256, 0, stream>>>(x, Ws1, Wn1, src, dst, xs, xn,
                                               loffT, bedge, n, e, K, B);
    k_agg1<<<K, 512, 0, stream>>>(bedge, loffT, xs, xn, b1, h, fsrc, lofsG, n, B);
    k_agg2_out<<<K, 512, 0, stream>>>(bedge, loffT, fsrc, lofsG, h,
                                      Ws2, Wn2, b2, out, n, B);
}